// Round 7
// baseline (242.199 us; speedup 1.0000x reference)
//
#include <hip/hip_runtime.h>

#define LRELU_ALPHA 0.3f
#define BN_EPS 1e-3f

using u16 = unsigned short;
using u32 = unsigned int;

typedef __attribute__((ext_vector_type(8))) short bf16x8;
typedef __attribute__((ext_vector_type(4))) float f32x4;

struct alignas(8) U16x4 { u16 x, y, z, w; };

__device__ __forceinline__ u16 f2bf(float f) {
  union { float f; u32 u; } v; v.f = f;
  u32 b = v.u;
  b += 0x7FFFu + ((b >> 16) & 1u);   // round-to-nearest-even
  return (u16)(b >> 16);
}
__device__ __forceinline__ float bf2f(u16 h) {
  union { u32 u; float f; } v; v.u = ((u32)h) << 16;
  return v.f;
}

typedef const __attribute__((address_space(1))) void* gas_ptr;
typedef __attribute__((address_space(3))) void* las_ptr;

__device__ __forceinline__ void gload16(const void* g, void* l) {
  __builtin_amdgcn_global_load_lds((gas_ptr)g, (las_ptr)l, 16, 0, 0);
}

// ---------------------------------------------------------------------------
// GEMM core A (BM=128, BN=128): single-buffered m97-style 2-barrier loop.
// LDS: A-tile [128][64] @0, B-tile [128][64] @8192 (elems). 32 KiB staging.
// 4 waves 2x2, each wave 64x64 (acc[4][4]).
// ---------------------------------------------------------------------------
template <int K>
__device__ __forceinline__ void gemm_core(const u16* __restrict__ A,
                                          const u16* __restrict__ B,
                                          u16* lds, f32x4 (&acc)[4][4]) {
  const int t = threadIdx.x, lane = t & 63, wid = t >> 6;
  const int wm = (wid >> 1) * 64, wn = (wid & 1) * 64;
  const int lrow = lane & 15, lk = (lane >> 4) * 8;
  const int r0 = t >> 3, ce = (t & 7) * 8, lo = wid * 512;
  u16* ldsA = lds;
  u16* ldsB = lds + 8192;
#pragma unroll 1
  for (int kt = 0; kt < K / 64; ++kt) {
    const u16* gA = A + kt * 64;
    const u16* gB = B + kt * 64;
#pragma unroll
    for (int cc = 0; cc < 4; ++cc) {
      gload16(gA + (size_t)(cc * 32 + r0) * K + ce, ldsA + cc * 2048 + lo);
      gload16(gB + (size_t)(cc * 32 + r0) * K + ce, ldsB + cc * 2048 + lo);
    }
    asm volatile("s_waitcnt vmcnt(0)" ::: "memory");
    __syncthreads();
#pragma unroll
    for (int kk = 0; kk < 2; ++kk) {
      bf16x8 a[4], b[4];
#pragma unroll
      for (int i = 0; i < 4; ++i)
        a[i] = *(const bf16x8*)(ldsA + (wm + i * 16 + lrow) * 64 + kk * 32 + lk);
#pragma unroll
      for (int i = 0; i < 4; ++i)
        b[i] = *(const bf16x8*)(ldsB + (wn + i * 16 + lrow) * 64 + kk * 32 + lk);
#pragma unroll
      for (int i = 0; i < 4; ++i)
#pragma unroll
        for (int j = 0; j < 4; ++j)
          acc[i][j] = __builtin_amdgcn_mfma_f32_16x16x32_bf16(a[i], b[j], acc[i][j], 0, 0, 0);
    }
    __syncthreads();
  }
}

// ---------------------------------------------------------------------------
// GEMM core B (BM=128, BN=64): 4 waves stacked on M (32 rows each), acc[2][4].
// LDS: A [128][64] @0 (16 KiB), B [64][64] @8192 (8 KiB). 24 KiB staging.
// ---------------------------------------------------------------------------
template <int K>
__device__ __forceinline__ void gemm_core64(const u16* __restrict__ A,
                                            const u16* __restrict__ B,
                                            u16* lds, f32x4 (&acc)[2][4]) {
  const int t = threadIdx.x, lane = t & 63, wid = t >> 6;
  const int wm = wid * 32;
  const int lrow = lane & 15, lk = (lane >> 4) * 8;
  const int r0 = t >> 3, ce = (t & 7) * 8, lo = wid * 512;
  u16* ldsA = lds;
  u16* ldsB = lds + 8192;
#pragma unroll 1
  for (int kt = 0; kt < K / 64; ++kt) {
    const u16* gA = A + kt * 64;
    const u16* gB = B + kt * 64;
#pragma unroll
    for (int cc = 0; cc < 4; ++cc)
      gload16(gA + (size_t)(cc * 32 + r0) * K + ce, ldsA + cc * 2048 + lo);
#pragma unroll
    for (int cc = 0; cc < 2; ++cc)
      gload16(gB + (size_t)(cc * 32 + r0) * K + ce, ldsB + cc * 2048 + lo);
    asm volatile("s_waitcnt vmcnt(0)" ::: "memory");
    __syncthreads();
#pragma unroll
    for (int kk = 0; kk < 2; ++kk) {
      bf16x8 a[2], b[4];
#pragma unroll
      for (int i = 0; i < 2; ++i)
        a[i] = *(const bf16x8*)(ldsA + (wm + i * 16 + lrow) * 64 + kk * 32 + lk);
#pragma unroll
      for (int j = 0; j < 4; ++j)
        b[j] = *(const bf16x8*)(ldsB + (j * 16 + lrow) * 64 + kk * 32 + lk);
#pragma unroll
      for (int i = 0; i < 2; ++i)
#pragma unroll
        for (int j = 0; j < 4; ++j)
          acc[i][j] = __builtin_amdgcn_mfma_f32_16x16x32_bf16(a[i], b[j], acc[i][j], 0, 0, 0);
    }
    __syncthreads();
  }
}

#define ACC_INIT(R)                                 \
  f32x4 acc[R][4];                                  \
  _Pragma("unroll") for (int i_ = 0; i_ < R; ++i_)  \
  _Pragma("unroll") for (int j_ = 0; j_ < 4; ++j_)  \
      acc[i_][j_] = {0.f, 0.f, 0.f, 0.f};

// ---------------------------------------------------------------------------
// k1: prep (BN2 fold, weight transpose/pack bf16) + h = BN1(x) -> bf16
// ---------------------------------------------------------------------------
__global__ __launch_bounds__(256) void k_prep_h(
    const float* __restrict__ w1, const float* __restrict__ wsk, const float* __restrict__ w2,
    const float* __restrict__ g1, const float* __restrict__ be1,
    const float* __restrict__ m1, const float* __restrict__ v1,
    const float* __restrict__ g2, const float* __restrict__ be2,
    const float* __restrict__ m2, const float* __restrict__ v2,
    const float* __restrict__ x,
    u16* __restrict__ wcatT, u16* __restrict__ w2T,
    float* __restrict__ s2, float* __restrict__ t2c, u16* __restrict__ h_bf) {
  int bid = blockIdx.x;
  if (bid < 768) {
    if (bid == 0) {
      int c = threadIdx.x;
      float a2 = g2[c] * rsqrtf(v2[c] + BN_EPS);
      s2[c] = a2;
      t2c[c] = be2[c] - m2[c] * a2;
    }
    int i = bid * 256 + threadIdx.x;
    if (i < 131072) {
      int co = i >> 8, ci = i & 255;
      const float* w = (co < 256) ? w1 : wsk;
      wcatT[i] = f2bf(w[ci * 256 + (co & 255)]);
    } else {
      int k = i - 131072;
      int co = k >> 8, ci = k & 255;
      w2T[k] = f2bf(w2[ci * 256 + co]);
    }
  } else {
    int base = (bid - 768) * 256 + threadIdx.x;        // float4 index base
    int c0 = (base << 2) & 255;                        // channel (constant across j)
    float sc[4], sh[4];
#pragma unroll
    for (int u = 0; u < 4; ++u) {
      int c = c0 + u;
      float a = g1[c] * rsqrtf(v1[c] + BN_EPS);
      sc[u] = a;
      sh[u] = be1[c] - m1[c] * a;
    }
#pragma unroll
    for (int j = 0; j < 16; ++j) {
      int k = j * 65536 + base;
      float4 v = ((const float4*)x)[k];
      U16x4 o = {f2bf(v.x * sc[0] + sh[0]), f2bf(v.y * sc[1] + sh[1]),
                 f2bf(v.z * sc[2] + sh[2]), f2bf(v.w * sc[3] + sh[3])};
      ((U16x4*)h_bf)[k] = o;
    }
  }
}

// ---------------------------------------------------------------------------
// k2: xw GEMM (hwT = (h @ wcat)^T per batch) INTERLEAVED with adj->bf16 convert
// ---------------------------------------------------------------------------
__global__ __launch_bounds__(256) void k_xw_cvt(const float* __restrict__ adj,
                                                u16* __restrict__ adj_bf,
                                                const u16* __restrict__ h_bf,
                                                const u16* __restrict__ wcatT,
                                                u16* __restrict__ hwT) {
  __shared__ u16 lds[17408];
  const int bid = blockIdx.x;
  const int r = bid % 5;
  if (r == 4) {                          // adj conversion stripe (BW-bound)
    const int stripe = bid / 5;
    const float4* src = (const float4*)adj + (size_t)stripe * 32768;
    U16x4* dst = (U16x4*)adj_bf + (size_t)stripe * 32768;
    for (int i = threadIdx.x; i < 32768; i += 256) {
      float4 v = src[i];
      U16x4 o = {f2bf(v.x), f2bf(v.y), f2bf(v.z), f2bf(v.w)};
      dst[i] = o;
    }
    return;
  }
  const int mt = bid / 5, nt = r;        // mt 0..127, nt 0..3
  ACC_INIT(4);
  gemm_core<256>(h_bf + (size_t)mt * 128 * 256, wcatT + (size_t)nt * 128 * 256, lds, acc);

  const int t = threadIdx.x, lane = t & 63, wid = t >> 6;
  const int row0 = (wid >> 1) * 64 + (lane >> 4) * 4;
  const int col0 = (wid & 1) * 64 + (lane & 15);
  __syncthreads();
  u16* tl = lds;                         // [co][136]
#pragma unroll
  for (int j = 0; j < 4; ++j) {
    int co_l = col0 + j * 16;
#pragma unroll
    for (int i = 0; i < 4; ++i)
#pragma unroll
      for (int q = 0; q < 4; ++q)
        tl[co_l * 136 + row0 + i * 16 + q] = f2bf(acc[i][j][q]);
  }
  __syncthreads();
  const int rw = t >> 4, seg = t & 15;
  const int b = mt >> 3, nb = (mt & 7) * 128;
#pragma unroll
  for (int p = 0; p < 8; ++p) {
    int co_l = p * 16 + rw;
    *(bf16x8*)(hwT + (((size_t)(b * 512 + nt * 128 + co_l)) << 10) + nb + seg * 8) =
        *(const bf16x8*)(tl + co_l * 136 + seg * 8);
  }
}

// ---------------------------------------------------------------------------
// big1 (conv1+skip fused): Y[b][n][c] = sum_m adj[b][n][m]*hw[b][m][c], c<512
// ---------------------------------------------------------------------------
__global__ __launch_bounds__(256) void k_big1(const u16* __restrict__ adj_bf,
                                              const u16* __restrict__ hwT,
                                              const float* __restrict__ b1,
                                              const float* __restrict__ bsk,
                                              const float* __restrict__ s2,
                                              const float* __restrict__ t2c,
                                              u16* __restrict__ u2b,
                                              u16* __restrict__ skipb) {
  __shared__ u16 lds[17408];
  ACC_INIT(4);
  const int mt = blockIdx.x, nt = blockIdx.y, bz = blockIdx.z;
  gemm_core<1024>(adj_bf + ((size_t)bz << 20) + (size_t)mt * 128 * 1024,
                  hwT    + ((size_t)bz << 19) + (size_t)nt * 128 * 1024, lds, acc);

  const int t = threadIdx.x, lane = t & 63, wid = t >> 6;
  const int row0 = (wid >> 1) * 64 + (lane >> 4) * 4;
  const int col0 = (wid & 1) * 64 + (lane & 15);
  const bool conv = (nt < 2);
  const int cb = (nt & 1) * 128;
  __syncthreads();
  u16* tl = lds;                         // [n][136]
#pragma unroll
  for (int j = 0; j < 4; ++j) {
    int cl = col0 + j * 16;
    int c = cb + cl;
    float bias = conv ? b1[c] : bsk[c];
    float sc = s2[c], tc = t2c[c];
#pragma unroll
    for (int i = 0; i < 4; ++i)
#pragma unroll
      for (int q = 0; q < 4; ++q) {
        float y = acc[i][j][q] + bias;
        float v;
        if (conv) {
          float u = (y >= 0.f) ? y : LRELU_ALPHA * y;
          v = fmaf(u, sc, tc);
        } else {
          v = y;
        }
        tl[(row0 + i * 16 + q) * 136 + cl] = f2bf(v);
      }
  }
  __syncthreads();
  u16* dstbase = (conv ? u2b : skipb) + ((size_t)bz << 18) + cb;
  const int rw = t >> 4, seg = t & 15;
  const int nb = mt * 128;
#pragma unroll
  for (int p = 0; p < 8; ++p) {
    int nl = p * 16 + rw;
    *(bf16x8*)(dstbase + ((size_t)(nb + nl) << 8) + seg * 8) =
        *(const bf16x8*)(tl + nl * 136 + seg * 8);
  }
}

// ---------------------------------------------------------------------------
// sm2 (operand-swapped, BN=64): t2T[b][co][n] = sum_c w2T[co][c]*u2[b][n][c]
// ---------------------------------------------------------------------------
__global__ __launch_bounds__(256) void k_sm2(const u16* __restrict__ w2T,
                                             const u16* __restrict__ u2b,
                                             u16* __restrict__ t2T) {
  __shared__ u16 lds[12288];
  ACC_INIT(2);
  const int mt = blockIdx.x, nt = blockIdx.y, bz = blockIdx.z;
  gemm_core64<256>(w2T + (size_t)mt * 128 * 256,
                   u2b + ((size_t)bz << 18) + (size_t)nt * 64 * 256, lds, acc);

  const int t = threadIdx.x, lane = t & 63, wid = t >> 6;
  const int row0 = wid * 32 + (lane >> 4) * 4;   // co local
  const int col0 = lane & 15;                    // n local
  __syncthreads();
  u16* tl = lds;                                 // [co 128][72]
#pragma unroll
  for (int j = 0; j < 4; ++j)
#pragma unroll
    for (int i = 0; i < 2; ++i)
#pragma unroll
      for (int q = 0; q < 4; ++q)
        tl[(row0 + i * 16 + q) * 72 + col0 + j * 16] = f2bf(acc[i][j][q]);
  __syncthreads();
  u16* base = t2T + ((size_t)bz << 18) + nt * 64;
  const int rw = t >> 3, seg = t & 7;            // full 64-col coverage: 32 rows/pass
#pragma unroll
  for (int p = 0; p < 4; ++p) {
    int co = p * 32 + rw;
    *(bf16x8*)(base + (((size_t)(mt * 128 + co)) << 10) + seg * 8) =
        *(const bf16x8*)(tl + co * 72 + seg * 8);
  }
}

// ---------------------------------------------------------------------------
// big2 (BN=64): out = lrelu( adj @ t2 + b2 ) + skip   (fp32, coalesced)
// ---------------------------------------------------------------------------
__global__ __launch_bounds__(256) void k_big2(const u16* __restrict__ adj_bf,
                                              const u16* __restrict__ t2T,
                                              const float* __restrict__ b2,
                                              const u16* __restrict__ skipb,
                                              float* __restrict__ outp) {
  __shared__ u16 lds[17408];
  ACC_INIT(2);
  const int mt = blockIdx.x, nt = blockIdx.y, bz = blockIdx.z;
  gemm_core64<1024>(adj_bf + ((size_t)bz << 20) + (size_t)mt * 128 * 1024,
                    t2T    + ((size_t)bz << 18) + (size_t)nt * 64 * 1024, lds, acc);

  const int t = threadIdx.x, lane = t & 63, wid = t >> 6;
  const int row0 = wid * 32 + (lane >> 4) * 4;   // n local
  const int col0 = lane & 15;                    // c local
  __syncthreads();
  float* tf = (float*)lds;                       // [n 128][68]
#pragma unroll
  for (int j = 0; j < 4; ++j) {
    int cl = col0 + j * 16;
    float bias = b2[nt * 64 + cl];
#pragma unroll
    for (int i = 0; i < 2; ++i)
#pragma unroll
      for (int q = 0; q < 4; ++q) {
        float y = acc[i][j][q] + bias;
        tf[(row0 + i * 16 + q) * 68 + cl] = (y >= 0.f) ? y : LRELU_ALPHA * y;
      }
  }
  __syncthreads();
  const int rw = t >> 4, seg = t & 15;           // full 64-col coverage: 16 rows/pass
#pragma unroll
  for (int p = 0; p < 8; ++p) {
    int nl = p * 16 + rw;
    size_t go = ((size_t)bz << 18) + ((size_t)(mt * 128 + nl) << 8) + nt * 64 + seg * 4;
    float4 v = *(const float4*)(tf + nl * 68 + seg * 4);
    U16x4 sk = *(const U16x4*)(skipb + go);
    float4 o = {v.x + bf2f(sk.x), v.y + bf2f(sk.y), v.z + bf2f(sk.z), v.w + bf2f(sk.w)};
    *(float4*)(outp + go) = o;
  }
}

// ---------------------------------------------------------------------------
extern "C" void kernel_launch(void* const* d_in, const int* in_sizes, int n_in,
                              void* d_out, int out_size, void* d_ws, size_t ws_size,
                              hipStream_t stream) {
  const float* x   = (const float*)d_in[0];
  const float* adj = (const float*)d_in[1];
  const float* g1  = (const float*)d_in[2];
  const float* be1 = (const float*)d_in[3];
  const float* mu1 = (const float*)d_in[4];
  const float* v1  = (const float*)d_in[5];
  const float* w1  = (const float*)d_in[6];
  const float* b1  = (const float*)d_in[7];
  const float* g2  = (const float*)d_in[8];
  const float* be2 = (const float*)d_in[9];
  const float* mu2 = (const float*)d_in[10];
  const float* v2  = (const float*)d_in[11];
  const float* w2  = (const float*)d_in[12];
  const float* b2  = (const float*)d_in[13];
  const float* wsk = (const float*)d_in[14];
  const float* bsk = (const float*)d_in[15];
  float* out = (float*)d_out;

  char* ws = (char*)d_ws;
  u16*   adj_bf = (u16*)(ws);                    // 33,554,432 B
  u16*   hwT    = (u16*)(ws + 33554432);         // 16,777,216 B
  u16*   h_bf   = (u16*)(ws + 50331648);         //  8,388,608 B
  u16*   u2b    = (u16*)(ws + 58720256);         //  8,388,608 B
  u16*   t2T    = (u16*)(ws + 67108864);         //  8,388,608 B
  u16*   skipb  = (u16*)(ws + 75497472);         //  8,388,608 B
  u16*   wcatT  = (u16*)(ws + 83886080);         //    262,144 B
  u16*   w2T    = (u16*)(ws + 84148224);         //    131,072 B
  float* s2     = (float*)(ws + 84281344);
  float* t2c    = (float*)(ws + 84282368);
  if (ws_size < 84283392) return;

  k_prep_h <<<1024, 256, 0, stream>>>(w1, wsk, w2, g1, be1, mu1, v1, g2, be2, mu2, v2,
                                      x, wcatT, w2T, s2, t2c, h_bf);
  k_xw_cvt <<<640, 256, 0, stream>>>(adj, adj_bf, h_bf, wcatT, hwT);
  k_big1<<<dim3(8, 4, 16),  256, 0, stream>>>(adj_bf, hwT, b1, bsk, s2, t2c, u2b, skipb);
  k_sm2 <<<dim3(2, 16, 16), 256, 0, stream>>>(w2T, u2b, t2T);
  k_big2<<<dim3(8, 4, 16),  256, 0, stream>>>(adj_bf, t2T, b2, skipb, out);
}

// Round 8
// 210.719 us; speedup vs baseline: 1.1494x; 1.1494x over previous
//
#include <hip/hip_runtime.h>

#define LRELU_ALPHA 0.3f
#define BN_EPS 1e-3f

using u16 = unsigned short;
using u32 = unsigned int;

typedef __attribute__((ext_vector_type(8))) short bf16x8;
typedef __attribute__((ext_vector_type(4))) float f32x4;

struct alignas(8) U16x4 { u16 x, y, z, w; };

__device__ __forceinline__ u16 f2bf(float f) {
  union { float f; u32 u; } v; v.f = f;
  u32 b = v.u;
  b += 0x7FFFu + ((b >> 16) & 1u);   // round-to-nearest-even
  return (u16)(b >> 16);
}
__device__ __forceinline__ float bf2f(u16 h) {
  union { u32 u; float f; } v; v.u = ((u32)h) << 16;
  return v.f;
}

typedef const __attribute__((address_space(1))) void* gas_ptr;
typedef __attribute__((address_space(3))) void* las_ptr;

__device__ __forceinline__ void gload16(const void* g, void* l) {
  __builtin_amdgcn_global_load_lds((gas_ptr)g, (las_ptr)l, 16, 0, 0);
}

// XCD-chunked bijective block swizzle for nwg = 512 (8 XCDs x 64 chunk)
__device__ __forceinline__ int xcd_swz512(int lid) {
  return (lid & 7) * 64 + (lid >> 3);
}

// ---------------------------------------------------------------------------
// GEMM core A (BM=128, BN=128): single-buffered m97-style 2-barrier loop.
// LDS: A-tile [128][64] @0, B-tile [128][64] @8192 (elems). 32 KiB staging.
// ---------------------------------------------------------------------------
template <int K>
__device__ __forceinline__ void gemm_core(const u16* __restrict__ A,
                                          const u16* __restrict__ B,
                                          u16* lds, f32x4 (&acc)[4][4]) {
  const int t = threadIdx.x, lane = t & 63, wid = t >> 6;
  const int wm = (wid >> 1) * 64, wn = (wid & 1) * 64;
  const int lrow = lane & 15, lk = (lane >> 4) * 8;
  const int r0 = t >> 3, ce = (t & 7) * 8, lo = wid * 512;
  u16* ldsA = lds;
  u16* ldsB = lds + 8192;
#pragma unroll 1
  for (int kt = 0; kt < K / 64; ++kt) {
    const u16* gA = A + kt * 64;
    const u16* gB = B + kt * 64;
#pragma unroll
    for (int cc = 0; cc < 4; ++cc) {
      gload16(gA + (size_t)(cc * 32 + r0) * K + ce, ldsA + cc * 2048 + lo);
      gload16(gB + (size_t)(cc * 32 + r0) * K + ce, ldsB + cc * 2048 + lo);
    }
    asm volatile("s_waitcnt vmcnt(0)" ::: "memory");
    __syncthreads();
#pragma unroll
    for (int kk = 0; kk < 2; ++kk) {
      bf16x8 a[4], b[4];
#pragma unroll
      for (int i = 0; i < 4; ++i)
        a[i] = *(const bf16x8*)(ldsA + (wm + i * 16 + lrow) * 64 + kk * 32 + lk);
#pragma unroll
      for (int i = 0; i < 4; ++i)
        b[i] = *(const bf16x8*)(ldsB + (wn + i * 16 + lrow) * 64 + kk * 32 + lk);
#pragma unroll
      for (int i = 0; i < 4; ++i)
#pragma unroll
        for (int j = 0; j < 4; ++j)
          acc[i][j] = __builtin_amdgcn_mfma_f32_16x16x32_bf16(a[i], b[j], acc[i][j], 0, 0, 0);
    }
    __syncthreads();
  }
}

// ---------------------------------------------------------------------------
// GEMM core B (BM=128, BN=64): 4 waves stacked on M (32 rows each), acc[2][4].
// LDS: A [128][64] @0 (16 KiB), B [64][64] @8192 (8 KiB). 24 KiB staging.
// ---------------------------------------------------------------------------
template <int K>
__device__ __forceinline__ void gemm_core64(const u16* __restrict__ A,
                                            const u16* __restrict__ B,
                                            u16* lds, f32x4 (&acc)[2][4]) {
  const int t = threadIdx.x, lane = t & 63, wid = t >> 6;
  const int wm = wid * 32;
  const int lrow = lane & 15, lk = (lane >> 4) * 8;
  const int r0 = t >> 3, ce = (t & 7) * 8, lo = wid * 512;
  u16* ldsA = lds;
  u16* ldsB = lds + 8192;
#pragma unroll 1
  for (int kt = 0; kt < K / 64; ++kt) {
    const u16* gA = A + kt * 64;
    const u16* gB = B + kt * 64;
#pragma unroll
    for (int cc = 0; cc < 4; ++cc)
      gload16(gA + (size_t)(cc * 32 + r0) * K + ce, ldsA + cc * 2048 + lo);
#pragma unroll
    for (int cc = 0; cc < 2; ++cc)
      gload16(gB + (size_t)(cc * 32 + r0) * K + ce, ldsB + cc * 2048 + lo);
    asm volatile("s_waitcnt vmcnt(0)" ::: "memory");
    __syncthreads();
#pragma unroll
    for (int kk = 0; kk < 2; ++kk) {
      bf16x8 a[2], b[4];
#pragma unroll
      for (int i = 0; i < 2; ++i)
        a[i] = *(const bf16x8*)(ldsA + (wm + i * 16 + lrow) * 64 + kk * 32 + lk);
#pragma unroll
      for (int j = 0; j < 4; ++j)
        b[j] = *(const bf16x8*)(ldsB + (j * 16 + lrow) * 64 + kk * 32 + lk);
#pragma unroll
      for (int i = 0; i < 2; ++i)
#pragma unroll
        for (int j = 0; j < 4; ++j)
          acc[i][j] = __builtin_amdgcn_mfma_f32_16x16x32_bf16(a[i], b[j], acc[i][j], 0, 0, 0);
    }
    __syncthreads();
  }
}

#define ACC_INIT(R)                                 \
  f32x4 acc[R][4];                                  \
  _Pragma("unroll") for (int i_ = 0; i_ < R; ++i_)  \
  _Pragma("unroll") for (int j_ = 0; j_ < 4; ++j_)  \
      acc[i_][j_] = {0.f, 0.f, 0.f, 0.f};

// ---------------------------------------------------------------------------
// k1: prep (BN2 fold, weight transpose/pack bf16) + h = BN1(x) -> bf16
// ---------------------------------------------------------------------------
__global__ __launch_bounds__(256) void k_prep_h(
    const float* __restrict__ w1, const float* __restrict__ wsk, const float* __restrict__ w2,
    const float* __restrict__ g1, const float* __restrict__ be1,
    const float* __restrict__ m1, const float* __restrict__ v1,
    const float* __restrict__ g2, const float* __restrict__ be2,
    const float* __restrict__ m2, const float* __restrict__ v2,
    const float* __restrict__ x,
    u16* __restrict__ wcatT, u16* __restrict__ w2T,
    float* __restrict__ s2, float* __restrict__ t2c, u16* __restrict__ h_bf) {
  int bid = blockIdx.x;
  if (bid < 768) {
    if (bid == 0) {
      int c = threadIdx.x;
      float a2 = g2[c] * rsqrtf(v2[c] + BN_EPS);
      s2[c] = a2;
      t2c[c] = be2[c] - m2[c] * a2;
    }
    int i = bid * 256 + threadIdx.x;
    if (i < 131072) {
      int co = i >> 8, ci = i & 255;
      const float* w = (co < 256) ? w1 : wsk;
      wcatT[i] = f2bf(w[ci * 256 + (co & 255)]);
    } else {
      int k = i - 131072;
      int co = k >> 8, ci = k & 255;
      w2T[k] = f2bf(w2[ci * 256 + co]);
    }
  } else {
    int base = (bid - 768) * 256 + threadIdx.x;        // float4 index base
    int c0 = (base << 2) & 255;                        // channel (constant across j)
    float sc[4], sh[4];
#pragma unroll
    for (int u = 0; u < 4; ++u) {
      int c = c0 + u;
      float a = g1[c] * rsqrtf(v1[c] + BN_EPS);
      sc[u] = a;
      sh[u] = be1[c] - m1[c] * a;
    }
#pragma unroll
    for (int j = 0; j < 16; ++j) {
      int k = j * 65536 + base;
      float4 v = ((const float4*)x)[k];
      U16x4 o = {f2bf(v.x * sc[0] + sh[0]), f2bf(v.y * sc[1] + sh[1]),
                 f2bf(v.z * sc[2] + sh[2]), f2bf(v.w * sc[3] + sh[3])};
      ((U16x4*)h_bf)[k] = o;
    }
  }
}

// ---------------------------------------------------------------------------
// k2: adj -> bf16, full-BW grid-stride (2048 blocks)
// ---------------------------------------------------------------------------
__global__ __launch_bounds__(256) void k_cvt(const float* __restrict__ adj,
                                             u16* __restrict__ adj_bf) {
  const int N4 = 4194304;   // 16*1024*1024 / 4
  int stride = gridDim.x * blockDim.x;
  for (int idx = blockIdx.x * blockDim.x + threadIdx.x; idx < N4; idx += stride) {
    float4 v = ((const float4*)adj)[idx];
    U16x4 o = {f2bf(v.x), f2bf(v.y), f2bf(v.z), f2bf(v.w)};
    ((U16x4*)adj_bf)[idx] = o;
  }
}

// ---------------------------------------------------------------------------
// k3: xw GEMM: hwT[b][co][n] = sum_c h[(b,n)][c] * wcatT[co][c]  (XCD-swizzled)
// ---------------------------------------------------------------------------
__global__ __launch_bounds__(256) void k_xw(const u16* __restrict__ h_bf,
                                            const u16* __restrict__ wcatT,
                                            u16* __restrict__ hwT) {
  __shared__ u16 lds[17408];
  const int wg = xcd_swz512(blockIdx.x);
  const int mt = wg >> 2, nt = wg & 3;   // 4 consecutive wg share the A-panel
  ACC_INIT(4);
  gemm_core<256>(h_bf + (size_t)mt * 128 * 256, wcatT + (size_t)nt * 128 * 256, lds, acc);

  const int t = threadIdx.x, lane = t & 63, wid = t >> 6;
  const int row0 = (wid >> 1) * 64 + (lane >> 4) * 4;
  const int col0 = (wid & 1) * 64 + (lane & 15);
  __syncthreads();
  u16* tl = lds;                         // [co][136]
#pragma unroll
  for (int j = 0; j < 4; ++j) {
    int co_l = col0 + j * 16;
#pragma unroll
    for (int i = 0; i < 4; ++i)
#pragma unroll
      for (int q = 0; q < 4; ++q)
        tl[co_l * 136 + row0 + i * 16 + q] = f2bf(acc[i][j][q]);
  }
  __syncthreads();
  const int rw = t >> 4, seg = t & 15;
  const int b = mt >> 3, nb = (mt & 7) * 128;
#pragma unroll
  for (int p = 0; p < 8; ++p) {
    int co_l = p * 16 + rw;
    *(bf16x8*)(hwT + (((size_t)(b * 512 + nt * 128 + co_l)) << 10) + nb + seg * 8) =
        *(const bf16x8*)(tl + co_l * 136 + seg * 8);
  }
}

// ---------------------------------------------------------------------------
// big1 (conv1+skip fused): Y[b][n][c] = sum_m adj[b][n][m]*hw[b][m][c], c<512
//   nt<2 : u2 = BN2(lrelu(Y+b1)) -> bf16 ; nt>=2 : skip = Y+bsk -> bf16
// ---------------------------------------------------------------------------
__global__ __launch_bounds__(256) void k_big1(const u16* __restrict__ adj_bf,
                                              const u16* __restrict__ hwT,
                                              const float* __restrict__ b1,
                                              const float* __restrict__ bsk,
                                              const float* __restrict__ s2,
                                              const float* __restrict__ t2c,
                                              u16* __restrict__ u2b,
                                              u16* __restrict__ skipb) {
  __shared__ u16 lds[17408];
  ACC_INIT(4);
  const int wg = xcd_swz512(blockIdx.x);
  const int mt = wg & 7, nt = (wg >> 3) & 3, bz = wg >> 5;
  gemm_core<1024>(adj_bf + ((size_t)bz << 20) + (size_t)mt * 128 * 1024,
                  hwT    + ((size_t)bz << 19) + (size_t)nt * 128 * 1024, lds, acc);

  const int t = threadIdx.x, lane = t & 63, wid = t >> 6;
  const int row0 = (wid >> 1) * 64 + (lane >> 4) * 4;
  const int col0 = (wid & 1) * 64 + (lane & 15);
  const bool conv = (nt < 2);
  const int cb = (nt & 1) * 128;
  __syncthreads();
  u16* tl = lds;                         // [n][136]
#pragma unroll
  for (int j = 0; j < 4; ++j) {
    int cl = col0 + j * 16;
    int c = cb + cl;
    float bias = conv ? b1[c] : bsk[c];
    float sc = s2[c], tc = t2c[c];
#pragma unroll
    for (int i = 0; i < 4; ++i)
#pragma unroll
      for (int q = 0; q < 4; ++q) {
        float y = acc[i][j][q] + bias;
        float v;
        if (conv) {
          float u = (y >= 0.f) ? y : LRELU_ALPHA * y;
          v = fmaf(u, sc, tc);
        } else {
          v = y;
        }
        tl[(row0 + i * 16 + q) * 136 + cl] = f2bf(v);
      }
  }
  __syncthreads();
  u16* dstbase = (conv ? u2b : skipb) + ((size_t)bz << 18) + cb;
  const int rw = t >> 4, seg = t & 15;
  const int nb = mt * 128;
#pragma unroll
  for (int p = 0; p < 8; ++p) {
    int nl = p * 16 + rw;
    *(bf16x8*)(dstbase + ((size_t)(nb + nl) << 8) + seg * 8) =
        *(const bf16x8*)(tl + nl * 136 + seg * 8);
  }
}

// ---------------------------------------------------------------------------
// sm2 (operand-swapped, BN=64): t2T[b][co][n] = sum_c w2T[co][c]*u2[b][n][c]
// ---------------------------------------------------------------------------
__global__ __launch_bounds__(256) void k_sm2(const u16* __restrict__ w2T,
                                             const u16* __restrict__ u2b,
                                             u16* __restrict__ t2T) {
  __shared__ u16 lds[12288];
  ACC_INIT(2);
  const int mt = blockIdx.x, nt = blockIdx.y, bz = blockIdx.z;
  gemm_core64<256>(w2T + (size_t)mt * 128 * 256,
                   u2b + ((size_t)bz << 18) + (size_t)nt * 64 * 256, lds, acc);

  const int t = threadIdx.x, lane = t & 63, wid = t >> 6;
  const int row0 = wid * 32 + (lane >> 4) * 4;   // co local
  const int col0 = lane & 15;                    // n local
  __syncthreads();
  u16* tl = lds;                                 // [co 128][72]
#pragma unroll
  for (int j = 0; j < 4; ++j)
#pragma unroll
    for (int i = 0; i < 2; ++i)
#pragma unroll
      for (int q = 0; q < 4; ++q)
        tl[(row0 + i * 16 + q) * 72 + col0 + j * 16] = f2bf(acc[i][j][q]);
  __syncthreads();
  u16* base = t2T + ((size_t)bz << 18) + nt * 64;
  const int rw = t >> 3, seg = t & 7;            // full 64-col coverage: 32 rows/pass
#pragma unroll
  for (int p = 0; p < 4; ++p) {
    int co = p * 32 + rw;
    *(bf16x8*)(base + (((size_t)(mt * 128 + co)) << 10) + seg * 8) =
        *(const bf16x8*)(tl + co * 72 + seg * 8);
  }
}

// ---------------------------------------------------------------------------
// big2 (BN=64): out = lrelu( adj @ t2 + b2 ) + skip   (fp32, coalesced)
// ---------------------------------------------------------------------------
__global__ __launch_bounds__(256) void k_big2(const u16* __restrict__ adj_bf,
                                              const u16* __restrict__ t2T,
                                              const float* __restrict__ b2,
                                              const u16* __restrict__ skipb,
                                              float* __restrict__ outp) {
  __shared__ u16 lds[17408];
  ACC_INIT(2);
  const int wg = xcd_swz512(blockIdx.x);
  const int mt = wg & 7, nt = (wg >> 3) & 3, bz = wg >> 5;
  gemm_core64<1024>(adj_bf + ((size_t)bz << 20) + (size_t)mt * 128 * 1024,
                    t2T    + ((size_t)bz << 18) + (size_t)nt * 64 * 1024, lds, acc);

  const int t = threadIdx.x, lane = t & 63, wid = t >> 6;
  const int row0 = wid * 32 + (lane >> 4) * 4;   // n local
  const int col0 = lane & 15;                    // c local
  __syncthreads();
  float* tf = (float*)lds;                       // [n 128][68]
#pragma unroll
  for (int j = 0; j < 4; ++j) {
    int cl = col0 + j * 16;
    float bias = b2[nt * 64 + cl];
#pragma unroll
    for (int i = 0; i < 2; ++i)
#pragma unroll
      for (int q = 0; q < 4; ++q) {
        float y = acc[i][j][q] + bias;
        tf[(row0 + i * 16 + q) * 68 + cl] = (y >= 0.f) ? y : LRELU_ALPHA * y;
      }
  }
  __syncthreads();
  const int rw = t >> 4, seg = t & 15;           // full 64-col coverage: 16 rows/pass
#pragma unroll
  for (int p = 0; p < 8; ++p) {
    int nl = p * 16 + rw;
    size_t go = ((size_t)bz << 18) + ((size_t)(mt * 128 + nl) << 8) + nt * 64 + seg * 4;
    float4 v = *(const float4*)(tf + nl * 68 + seg * 4);
    U16x4 sk = *(const U16x4*)(skipb + go);
    float4 o = {v.x + bf2f(sk.x), v.y + bf2f(sk.y), v.z + bf2f(sk.z), v.w + bf2f(sk.w)};
    *(float4*)(outp + go) = o;
  }
}

// ---------------------------------------------------------------------------
extern "C" void kernel_launch(void* const* d_in, const int* in_sizes, int n_in,
                              void* d_out, int out_size, void* d_ws, size_t ws_size,
                              hipStream_t stream) {
  const float* x   = (const float*)d_in[0];
  const float* adj = (const float*)d_in[1];
  const float* g1  = (const float*)d_in[2];
  const float* be1 = (const float*)d_in[3];
  const float* mu1 = (const float*)d_in[4];
  const float* v1  = (const float*)d_in[5];
  const float* w1  = (const float*)d_in[6];
  const float* b1  = (const float*)d_in[7];
  const float* g2  = (const float*)d_in[8];
  const float* be2 = (const float*)d_in[9];
  const float* mu2 = (const float*)d_in[10];
  const float* v2  = (const float*)d_in[11];
  const float* w2  = (const float*)d_in[12];
  const float* b2  = (const float*)d_in[13];
  const float* wsk = (const float*)d_in[14];
  const float* bsk = (const float*)d_in[15];
  float* out = (float*)d_out;

  char* ws = (char*)d_ws;
  u16*   adj_bf = (u16*)(ws);                    // 33,554,432 B
  u16*   hwT    = (u16*)(ws + 33554432);         // 16,777,216 B
  u16*   h_bf   = (u16*)(ws + 50331648);         //  8,388,608 B
  u16*   u2b    = (u16*)(ws + 58720256);         //  8,388,608 B
  u16*   t2T    = (u16*)(ws + 67108864);         //  8,388,608 B
  u16*   skipb  = (u16*)(ws + 75497472);         //  8,388,608 B
  u16*   wcatT  = (u16*)(ws + 83886080);         //    262,144 B
  u16*   w2T    = (u16*)(ws + 84148224);         //    131,072 B
  float* s2     = (float*)(ws + 84281344);
  float* t2c    = (float*)(ws + 84282368);
  if (ws_size < 84283392) return;

  k_prep_h <<<1024, 256, 0, stream>>>(w1, wsk, w2, g1, be1, mu1, v1, g2, be2, mu2, v2,
                                      x, wcatT, w2T, s2, t2c, h_bf);
  k_cvt    <<<2048, 256, 0, stream>>>(adj, adj_bf);
  k_xw     <<<512,  256, 0, stream>>>(h_bf, wcatT, hwT);
  k_big1   <<<512,  256, 0, stream>>>(adj_bf, hwT, b1, bsk, s2, t2c, u2b, skipb);
  k_sm2 <<<dim3(2, 16, 16), 256, 0, stream>>>(w2T, u2b, t2T);
  k_big2   <<<512,  256, 0, stream>>>(adj_bf, t2T, b2, skipb, out);
}

// Round 9
// 205.359 us; speedup vs baseline: 1.1794x; 1.0261x over previous
//
#include <hip/hip_runtime.h>

#define LRELU_ALPHA 0.3f
#define BN_EPS 1e-3f

using u16 = unsigned short;
using u32 = unsigned int;

typedef __attribute__((ext_vector_type(8))) short bf16x8;
typedef __attribute__((ext_vector_type(4))) float f32x4;

struct alignas(8) U16x4 { u16 x, y, z, w; };

__device__ __forceinline__ u16 f2bf(float f) {
  union { float f; u32 u; } v; v.f = f;
  u32 b = v.u;
  b += 0x7FFFu + ((b >> 16) & 1u);   // round-to-nearest-even
  return (u16)(b >> 16);
}
__device__ __forceinline__ float bf2f(u16 h) {
  union { u32 u; float f; } v; v.u = ((u32)h) << 16;
  return v.f;
}

typedef const __attribute__((address_space(1))) void* gas_ptr;
typedef __attribute__((address_space(3))) void* las_ptr;

__device__ __forceinline__ void gload16(const void* g, void* l) {
  __builtin_amdgcn_global_load_lds((gas_ptr)g, (las_ptr)l, 16, 0, 0);
}

// XCD-chunked bijective block swizzle for nwg = 512 (8 XCDs x 64 chunk)
__device__ __forceinline__ int xcd_swz512(int lid) {
  return (lid & 7) * 64 + (lid >> 3);
}

// ---------------------------------------------------------------------------
// GEMM core A (BM=128, BN=128): single-buffered 2-barrier loop. 32 KiB staging.
// ---------------------------------------------------------------------------
template <int K>
__device__ __forceinline__ void gemm_core(const u16* __restrict__ A,
                                          const u16* __restrict__ B,
                                          u16* lds, f32x4 (&acc)[4][4]) {
  const int t = threadIdx.x, lane = t & 63, wid = t >> 6;
  const int wm = (wid >> 1) * 64, wn = (wid & 1) * 64;
  const int lrow = lane & 15, lk = (lane >> 4) * 8;
  const int r0 = t >> 3, ce = (t & 7) * 8, lo = wid * 512;
  u16* ldsA = lds;
  u16* ldsB = lds + 8192;
#pragma unroll 1
  for (int kt = 0; kt < K / 64; ++kt) {
    const u16* gA = A + kt * 64;
    const u16* gB = B + kt * 64;
#pragma unroll
    for (int cc = 0; cc < 4; ++cc) {
      gload16(gA + (size_t)(cc * 32 + r0) * K + ce, ldsA + cc * 2048 + lo);
      gload16(gB + (size_t)(cc * 32 + r0) * K + ce, ldsB + cc * 2048 + lo);
    }
    asm volatile("s_waitcnt vmcnt(0)" ::: "memory");
    __syncthreads();
#pragma unroll
    for (int kk = 0; kk < 2; ++kk) {
      bf16x8 a[4], b[4];
#pragma unroll
      for (int i = 0; i < 4; ++i)
        a[i] = *(const bf16x8*)(ldsA + (wm + i * 16 + lrow) * 64 + kk * 32 + lk);
#pragma unroll
      for (int i = 0; i < 4; ++i)
        b[i] = *(const bf16x8*)(ldsB + (wn + i * 16 + lrow) * 64 + kk * 32 + lk);
#pragma unroll
      for (int i = 0; i < 4; ++i)
#pragma unroll
        for (int j = 0; j < 4; ++j)
          acc[i][j] = __builtin_amdgcn_mfma_f32_16x16x32_bf16(a[i], b[j], acc[i][j], 0, 0, 0);
    }
    __syncthreads();
  }
}

// ---------------------------------------------------------------------------
// GEMM core B (BM=128, BN=64): 4 waves stacked on M (32 rows each), acc[2][4].
// ---------------------------------------------------------------------------
template <int K>
__device__ __forceinline__ void gemm_core64(const u16* __restrict__ A,
                                            const u16* __restrict__ B,
                                            u16* lds, f32x4 (&acc)[2][4]) {
  const int t = threadIdx.x, lane = t & 63, wid = t >> 6;
  const int wm = wid * 32;
  const int lrow = lane & 15, lk = (lane >> 4) * 8;
  const int r0 = t >> 3, ce = (t & 7) * 8, lo = wid * 512;
  u16* ldsA = lds;
  u16* ldsB = lds + 8192;
#pragma unroll 1
  for (int kt = 0; kt < K / 64; ++kt) {
    const u16* gA = A + kt * 64;
    const u16* gB = B + kt * 64;
#pragma unroll
    for (int cc = 0; cc < 4; ++cc)
      gload16(gA + (size_t)(cc * 32 + r0) * K + ce, ldsA + cc * 2048 + lo);
#pragma unroll
    for (int cc = 0; cc < 2; ++cc)
      gload16(gB + (size_t)(cc * 32 + r0) * K + ce, ldsB + cc * 2048 + lo);
    asm volatile("s_waitcnt vmcnt(0)" ::: "memory");
    __syncthreads();
#pragma unroll
    for (int kk = 0; kk < 2; ++kk) {
      bf16x8 a[2], b[4];
#pragma unroll
      for (int i = 0; i < 2; ++i)
        a[i] = *(const bf16x8*)(ldsA + (wm + i * 16 + lrow) * 64 + kk * 32 + lk);
#pragma unroll
      for (int j = 0; j < 4; ++j)
        b[j] = *(const bf16x8*)(ldsB + (j * 16 + lrow) * 64 + kk * 32 + lk);
#pragma unroll
      for (int i = 0; i < 2; ++i)
#pragma unroll
        for (int j = 0; j < 4; ++j)
          acc[i][j] = __builtin_amdgcn_mfma_f32_16x16x32_bf16(a[i], b[j], acc[i][j], 0, 0, 0);
    }
    __syncthreads();
  }
}

// ---------------------------------------------------------------------------
// GEMM core C (BM=128, dual BN=64): shared A-tile, two B-panels, two accs.
// LDS: A @0 (16 KiB), B1 @8192 (8 KiB), B2 @12288 (8 KiB). 32 KiB staging.
// ---------------------------------------------------------------------------
template <int K>
__device__ __forceinline__ void gemm_core64x2(const u16* __restrict__ A,
                                              const u16* __restrict__ B1,
                                              const u16* __restrict__ B2,
                                              u16* lds, f32x4 (&acc1)[2][4],
                                              f32x4 (&acc2)[2][4]) {
  const int t = threadIdx.x, lane = t & 63, wid = t >> 6;
  const int wm = wid * 32;
  const int lrow = lane & 15, lk = (lane >> 4) * 8;
  const int r0 = t >> 3, ce = (t & 7) * 8, lo = wid * 512;
  u16* ldsA  = lds;
  u16* ldsB1 = lds + 8192;
  u16* ldsB2 = lds + 12288;
#pragma unroll 1
  for (int kt = 0; kt < K / 64; ++kt) {
    const u16* gA  = A  + kt * 64;
    const u16* gB1 = B1 + kt * 64;
    const u16* gB2 = B2 + kt * 64;
#pragma unroll
    for (int cc = 0; cc < 4; ++cc)
      gload16(gA + (size_t)(cc * 32 + r0) * K + ce, ldsA + cc * 2048 + lo);
#pragma unroll
    for (int cc = 0; cc < 2; ++cc) {
      gload16(gB1 + (size_t)(cc * 32 + r0) * K + ce, ldsB1 + cc * 2048 + lo);
      gload16(gB2 + (size_t)(cc * 32 + r0) * K + ce, ldsB2 + cc * 2048 + lo);
    }
    asm volatile("s_waitcnt vmcnt(0)" ::: "memory");
    __syncthreads();
#pragma unroll
    for (int kk = 0; kk < 2; ++kk) {
      bf16x8 a[2], b1[4], b2[4];
#pragma unroll
      for (int i = 0; i < 2; ++i)
        a[i] = *(const bf16x8*)(ldsA + (wm + i * 16 + lrow) * 64 + kk * 32 + lk);
#pragma unroll
      for (int j = 0; j < 4; ++j) {
        b1[j] = *(const bf16x8*)(ldsB1 + (j * 16 + lrow) * 64 + kk * 32 + lk);
        b2[j] = *(const bf16x8*)(ldsB2 + (j * 16 + lrow) * 64 + kk * 32 + lk);
      }
#pragma unroll
      for (int i = 0; i < 2; ++i)
#pragma unroll
        for (int j = 0; j < 4; ++j) {
          acc1[i][j] = __builtin_amdgcn_mfma_f32_16x16x32_bf16(a[i], b1[j], acc1[i][j], 0, 0, 0);
          acc2[i][j] = __builtin_amdgcn_mfma_f32_16x16x32_bf16(a[i], b2[j], acc2[i][j], 0, 0, 0);
        }
    }
    __syncthreads();
  }
}

#define ACC_INIT_N(name, R)                          \
  f32x4 name[R][4];                                  \
  _Pragma("unroll") for (int i_ = 0; i_ < R; ++i_)   \
  _Pragma("unroll") for (int j_ = 0; j_ < 4; ++j_)   \
      name[i_][j_] = {0.f, 0.f, 0.f, 0.f};

// ---------------------------------------------------------------------------
// k_pre: fused streaming prep — weights pack + BN2 fold (blocks 0..767),
// h = BN1(x) -> bf16 (blocks 768..1023), adj -> bf16 (blocks 1024..3071).
// All parts independent; all BW-bound.
// ---------------------------------------------------------------------------
__global__ __launch_bounds__(256) void k_pre(
    const float* __restrict__ w1, const float* __restrict__ wsk, const float* __restrict__ w2,
    const float* __restrict__ g1, const float* __restrict__ be1,
    const float* __restrict__ m1, const float* __restrict__ v1,
    const float* __restrict__ g2, const float* __restrict__ be2,
    const float* __restrict__ m2, const float* __restrict__ v2,
    const float* __restrict__ x, const float* __restrict__ adj,
    u16* __restrict__ wcatT, u16* __restrict__ w2T,
    float* __restrict__ s2, float* __restrict__ t2c,
    u16* __restrict__ h_bf, u16* __restrict__ adj_bf) {
  int bid = blockIdx.x;
  if (bid < 768) {
    if (bid == 0) {
      int c = threadIdx.x;
      float a2 = g2[c] * rsqrtf(v2[c] + BN_EPS);
      s2[c] = a2;
      t2c[c] = be2[c] - m2[c] * a2;
    }
    int i = bid * 256 + threadIdx.x;
    if (i < 131072) {
      int co = i >> 8, ci = i & 255;
      const float* w = (co < 256) ? w1 : wsk;
      wcatT[i] = f2bf(w[ci * 256 + (co & 255)]);
    } else {
      int k = i - 131072;
      int co = k >> 8, ci = k & 255;
      w2T[k] = f2bf(w2[ci * 256 + co]);
    }
  } else if (bid < 1024) {
    int base = (bid - 768) * 256 + threadIdx.x;        // float4 index base
    int c0 = (base << 2) & 255;                        // channel fixed across j
    float sc[4], sh[4];
#pragma unroll
    for (int u = 0; u < 4; ++u) {
      int c = c0 + u;
      float a = g1[c] * rsqrtf(v1[c] + BN_EPS);
      sc[u] = a;
      sh[u] = be1[c] - m1[c] * a;
    }
#pragma unroll
    for (int j = 0; j < 16; ++j) {
      int k = j * 65536 + base;
      float4 v = ((const float4*)x)[k];
      U16x4 o = {f2bf(v.x * sc[0] + sh[0]), f2bf(v.y * sc[1] + sh[1]),
                 f2bf(v.z * sc[2] + sh[2]), f2bf(v.w * sc[3] + sh[3])};
      ((U16x4*)h_bf)[k] = o;
    }
  } else {
    const int N4 = 4194304;   // 16*1024*1024 / 4
    int idx = (bid - 1024) * 256 + threadIdx.x;
    const int stride = 2048 * 256;
#pragma unroll 1
    for (; idx < N4; idx += stride) {
      float4 v = ((const float4*)adj)[idx];
      U16x4 o = {f2bf(v.x), f2bf(v.y), f2bf(v.z), f2bf(v.w)};
      ((U16x4*)adj_bf)[idx] = o;
    }
  }
}

// ---------------------------------------------------------------------------
// k_xw: hwT[b][co][n] = sum_c h[(b,n)][c] * wcatT[co][c]   (XCD-swizzled)
// ---------------------------------------------------------------------------
__global__ __launch_bounds__(256) void k_xw(const u16* __restrict__ h_bf,
                                            const u16* __restrict__ wcatT,
                                            u16* __restrict__ hwT) {
  __shared__ u16 lds[17408];
  const int wg = xcd_swz512(blockIdx.x);
  const int mt = wg >> 2, nt = wg & 3;
  ACC_INIT_N(acc, 4);
  gemm_core<256>(h_bf + (size_t)mt * 128 * 256, wcatT + (size_t)nt * 128 * 256, lds, acc);

  const int t = threadIdx.x, lane = t & 63, wid = t >> 6;
  const int row0 = (wid >> 1) * 64 + (lane >> 4) * 4;
  const int col0 = (wid & 1) * 64 + (lane & 15);
  __syncthreads();
  u16* tl = lds;                         // [co][136]
#pragma unroll
  for (int j = 0; j < 4; ++j) {
    int co_l = col0 + j * 16;
#pragma unroll
    for (int i = 0; i < 4; ++i)
#pragma unroll
      for (int q = 0; q < 4; ++q)
        tl[co_l * 136 + row0 + i * 16 + q] = f2bf(acc[i][j][q]);
  }
  __syncthreads();
  const int rw = t >> 4, seg = t & 15;
  const int b = mt >> 3, nb = (mt & 7) * 128;
#pragma unroll
  for (int p = 0; p < 8; ++p) {
    int co_l = p * 16 + rw;
    *(bf16x8*)(hwT + (((size_t)(b * 512 + nt * 128 + co_l)) << 10) + nb + seg * 8) =
        *(const bf16x8*)(tl + co_l * 136 + seg * 8);
  }
}

// ---------------------------------------------------------------------------
// big1 (conv-only): u2 = BN2(lrelu(adj @ hw_conv + b1)) -> bf16
// grid 512: mt n-tile(128), nt c-tile(64), bz batch (XCD-swizzled)
// ---------------------------------------------------------------------------
__global__ __launch_bounds__(256) void k_big1(const u16* __restrict__ adj_bf,
                                              const u16* __restrict__ hwT,
                                              const float* __restrict__ b1,
                                              const float* __restrict__ s2,
                                              const float* __restrict__ t2c,
                                              u16* __restrict__ u2b) {
  __shared__ u16 lds[17408];
  ACC_INIT_N(acc, 2);
  const int wg = xcd_swz512(blockIdx.x);
  const int mt = wg & 7, nt = (wg >> 3) & 3, bz = wg >> 5;
  gemm_core64<1024>(adj_bf + ((size_t)bz << 20) + (size_t)mt * 128 * 1024,
                    hwT    + ((size_t)bz << 19) + ((size_t)(nt * 64) << 10), lds, acc);

  const int t = threadIdx.x, lane = t & 63, wid = t >> 6;
  const int row0 = wid * 32 + (lane >> 4) * 4;   // n local
  const int col0 = lane & 15;                    // c local
  __syncthreads();
  u16* tl = lds;                                 // [n 128][72]
#pragma unroll
  for (int j = 0; j < 4; ++j) {
    int cl = col0 + j * 16;
    int c = nt * 64 + cl;
    float bias = b1[c], sc = s2[c], tc = t2c[c];
#pragma unroll
    for (int i = 0; i < 2; ++i)
#pragma unroll
      for (int q = 0; q < 4; ++q) {
        float y = acc[i][j][q] + bias;
        float u = (y >= 0.f) ? y : LRELU_ALPHA * y;
        tl[(row0 + i * 16 + q) * 72 + cl] = f2bf(fmaf(u, sc, tc));
      }
  }
  __syncthreads();
  u16* dstbase = u2b + ((size_t)bz << 18) + nt * 64;
  const int rw = t >> 3, seg = t & 7;            // 32 rows/pass, 8x8 elems/row
#pragma unroll
  for (int p = 0; p < 4; ++p) {
    int nl = p * 32 + rw;
    *(bf16x8*)(dstbase + ((size_t)(mt * 128 + nl) << 8) + seg * 8) =
        *(const bf16x8*)(tl + nl * 72 + seg * 8);
  }
}

// ---------------------------------------------------------------------------
// sm2 (operand-swapped, BN=64): t2T[b][co][n] = sum_c w2T[co][c]*u2[b][n][c]
// ---------------------------------------------------------------------------
__global__ __launch_bounds__(256) void k_sm2(const u16* __restrict__ w2T,
                                             const u16* __restrict__ u2b,
                                             u16* __restrict__ t2T) {
  __shared__ u16 lds[12288];
  ACC_INIT_N(acc, 2);
  const int mt = blockIdx.x, nt = blockIdx.y, bz = blockIdx.z;
  gemm_core64<256>(w2T + (size_t)mt * 128 * 256,
                   u2b + ((size_t)bz << 18) + (size_t)nt * 64 * 256, lds, acc);

  const int t = threadIdx.x, lane = t & 63, wid = t >> 6;
  const int row0 = wid * 32 + (lane >> 4) * 4;   // co local
  const int col0 = lane & 15;                    // n local
  __syncthreads();
  u16* tl = lds;                                 // [co 128][72]
#pragma unroll
  for (int j = 0; j < 4; ++j)
#pragma unroll
    for (int i = 0; i < 2; ++i)
#pragma unroll
      for (int q = 0; q < 4; ++q)
        tl[(row0 + i * 16 + q) * 72 + col0 + j * 16] = f2bf(acc[i][j][q]);
  __syncthreads();
  u16* base = t2T + ((size_t)bz << 18) + nt * 64;
  const int rw = t >> 3, seg = t & 7;
#pragma unroll
  for (int p = 0; p < 4; ++p) {
    int co = p * 32 + rw;
    *(bf16x8*)(base + (((size_t)(mt * 128 + co)) << 10) + seg * 8) =
        *(const bf16x8*)(tl + co * 72 + seg * 8);
  }
}

// ---------------------------------------------------------------------------
// big2 (dual-B): out = lrelu(adj@t2 + b2) + (adj@hw_skip + bsk)   (fp32)
// grid 512: mt n-tile(128), nt c-tile(64), bz batch (XCD-swizzled)
// ---------------------------------------------------------------------------
__global__ __launch_bounds__(256) void k_big2(const u16* __restrict__ adj_bf,
                                              const u16* __restrict__ t2T,
                                              const u16* __restrict__ hwT,
                                              const float* __restrict__ b2,
                                              const float* __restrict__ bsk,
                                              float* __restrict__ outp) {
  __shared__ u16 lds[17408];
  ACC_INIT_N(acc1, 2);
  ACC_INIT_N(acc2, 2);
  const int wg = xcd_swz512(blockIdx.x);
  const int mt = wg & 7, nt = (wg >> 3) & 3, bz = wg >> 5;
  gemm_core64x2<1024>(adj_bf + ((size_t)bz << 20) + (size_t)mt * 128 * 1024,
                      t2T    + ((size_t)bz << 18) + ((size_t)(nt * 64) << 10),
                      hwT    + ((size_t)bz << 19) + ((size_t)(256 + nt * 64) << 10),
                      lds, acc1, acc2);

  const int t = threadIdx.x, lane = t & 63, wid = t >> 6;
  const int row0 = wid * 32 + (lane >> 4) * 4;   // n local
  const int col0 = lane & 15;                    // c local
  __syncthreads();
  float* tf = (float*)lds;                       // [n 128][68]
#pragma unroll
  for (int j = 0; j < 4; ++j) {
    int cl = col0 + j * 16;
    int c = nt * 64 + cl;
    float bc = b2[c], bs = bsk[c];
#pragma unroll
    for (int i = 0; i < 2; ++i)
#pragma unroll
      for (int q = 0; q < 4; ++q) {
        float y = acc1[i][j][q] + bc;
        float conv = (y >= 0.f) ? y : LRELU_ALPHA * y;
        tf[(row0 + i * 16 + q) * 68 + cl] = conv + acc2[i][j][q] + bs;
      }
  }
  __syncthreads();
  const int rw = t >> 4, seg = t & 15;           // 16 rows/pass, 16x4 floats/row
#pragma unroll
  for (int p = 0; p < 8; ++p) {
    int nl = p * 16 + rw;
    size_t go = ((size_t)bz << 18) + ((size_t)(mt * 128 + nl) << 8) + nt * 64 + seg * 4;
    *(float4*)(outp + go) = *(const float4*)(tf + nl * 68 + seg * 4);
  }
}

// ---------------------------------------------------------------------------
extern "C" void kernel_launch(void* const* d_in, const int* in_sizes, int n_in,
                              void* d_out, int out_size, void* d_ws, size_t ws_size,
                              hipStream_t stream) {
  const float* x   = (const float*)d_in[0];
  const float* adj = (const float*)d_in[1];
  const float* g1  = (const float*)d_in[2];
  const float* be1 = (const float*)d_in[3];
  const float* mu1 = (const float*)d_in[4];
  const float* v1  = (const float*)d_in[5];
  const float* w1  = (const float*)d_in[6];
  const float* b1  = (const float*)d_in[7];
  const float* g2  = (const float*)d_in[8];
  const float* be2 = (const float*)d_in[9];
  const float* mu2 = (const float*)d_in[10];
  const float* v2  = (const float*)d_in[11];
  const float* w2  = (const float*)d_in[12];
  const float* b2  = (const float*)d_in[13];
  const float* wsk = (const float*)d_in[14];
  const float* bsk = (const float*)d_in[15];
  float* out = (float*)d_out;

  char* ws = (char*)d_ws;
  u16*   adj_bf = (u16*)(ws);                    // 33,554,432 B
  u16*   hwT    = (u16*)(ws + 33554432);         // 16,777,216 B
  u16*   h_bf   = (u16*)(ws + 50331648);         //  8,388,608 B
  u16*   u2b    = (u16*)(ws + 58720256);         //  8,388,608 B
  u16*   t2T    = (u16*)(ws + 67108864);         //  8,388,608 B
  u16*   wcatT  = (u16*)(ws + 83886080);         //    262,144 B
  u16*   w2T    = (u16*)(ws + 84148224);         //    131,072 B
  float* s2     = (float*)(ws + 84281344);
  float* t2c    = (float*)(ws + 84282368);
  if (ws_size < 84283392) return;

  k_pre  <<<3072, 256, 0, stream>>>(w1, wsk, w2, g1, be1, mu1, v1, g2, be2, mu2, v2,
                                    x, adj, wcatT, w2T, s2, t2c, h_bf, adj_bf);
  k_xw   <<<512,  256, 0, stream>>>(h_bf, wcatT, hwT);
  k_big1 <<<512,  256, 0, stream>>>(adj_bf, hwT, b1, s2, t2c, u2b);
  k_sm2  <<<dim3(2, 16, 16), 256, 0, stream>>>(w2T, u2b, t2T);
  k_big2 <<<512,  256, 0, stream>>>(adj_bf, t2T, hwT, b2, bsk, out);
}